// Round 8
// baseline (329.367 us; speedup 1.0000x reference)
//
#include <hip/hip_runtime.h>

#define VOC 50257
#define EMB 128
#define NMEM 8192
#define TQ 50
#define TM 50
#define NHOPS 3

#define MEM_ROWS 4                    // rows per k_mem_u block (1 per wave)
#define NMEMBLK (NMEM / MEM_ROWS)     // 2048
#define NHOP 256                      // blocks per hop kernel
#define HROWS (NMEM / NHOP)           // 32 rows per hop block
#define LOGROWS 64                    // vocab rows per k_logits block
#define NLOG ((VOC + LOGROWS - 1) / LOGROWS)   // 786

// ---------------- workspace layout (float offsets) ----------------
#define WS_U      0                            // u[4][128]: u0..u3
#define WS_MIN    (WS_U + 4*EMB)
#define WS_MOUT   (WS_MIN + NMEM*EMB)
#define WS_BSUM   (WS_MOUT + NMEM*EMB)         // bsum[3][NHOP]
#define WS_WPART  (WS_BSUM + 3*NHOP)           // wpart[3][NHOP][EMB]
#define WS_LOGITS (WS_WPART + 3*NHOP*EMB)
#define WS_BPART  (WS_LOGITS + VOC)

// ================= k_mem_u: unchanged from round 6 (proven) =================
__global__ void k_mem_u(const int* __restrict__ story, const int* __restrict__ query,
                        const float* __restrict__ Wa, const float* __restrict__ Wc,
                        const float* __restrict__ Wb, const float* __restrict__ TA,
                        const float* __restrict__ TC, float* __restrict__ min_,
                        float* __restrict__ mout, float* __restrict__ u) {
    int b = blockIdx.x;
    int t = threadIdx.x;
    if (b == NMEMBLK) {
        __shared__ int q[TQ];
        if (t < TQ) q[t] = query[t];
        __syncthreads();
        if (t < EMB) {
            float acc = 0.f;
            for (int i = 0; i < TQ; ++i) acc += Wb[q[i] * EMB + t];
            u[t] = acc;
        }
        return;
    }
    __shared__ int toks[MEM_ROWS * TM];
    if (t < MEM_ROWS * TM) toks[t] = story[b * MEM_ROWS * TM + t];
    __syncthreads();
    int w = t >> 6;
    int lane = t & 63;
    int half = lane >> 5;
    int l = lane & 31;
    int n = b * MEM_ROWS + w;
    float4 a = {0.f, 0.f, 0.f, 0.f};
    float4 c = {0.f, 0.f, 0.f, 0.f};
    #pragma unroll
    for (int tt = 0; tt < TM / 2; ++tt) {
        int tok = toks[w * TM + 2 * tt + half];
        float4 va = ((const float4*)(Wa + tok * EMB))[l];
        float4 vc = ((const float4*)(Wc + tok * EMB))[l];
        a.x += va.x; a.y += va.y; a.z += va.z; a.w += va.w;
        c.x += vc.x; c.y += vc.y; c.z += vc.z; c.w += vc.w;
    }
    a.x += __shfl_xor(a.x, 32); a.y += __shfl_xor(a.y, 32);
    a.z += __shfl_xor(a.z, 32); a.w += __shfl_xor(a.w, 32);
    c.x += __shfl_xor(c.x, 32); c.y += __shfl_xor(c.y, 32);
    c.z += __shfl_xor(c.z, 32); c.w += __shfl_xor(c.w, 32);
    if (half == 0) {
        float4 tv = ((const float4*)(TA + n * EMB))[l];
        a.x += tv.x; a.y += tv.y; a.z += tv.z; a.w += tv.w;
        ((float4*)(min_ + n * EMB))[l] = a;
    } else {
        float4 tv = ((const float4*)(TC + n * EMB))[l];
        c.x += tv.x; c.y += tv.y; c.z += tv.z; c.w += tv.w;
        ((float4*)(mout + n * EMB))[l] = c;
    }
}

// ===== redundant finalize: u_new (LDS unew[128]) from prev-hop partials =====
// Every block executes this identically (deterministic); optional global write.
__device__ __forceinline__ void finalize_u(const float* __restrict__ bsumP,
                                           const float* __restrict__ wpartP,
                                           const float* __restrict__ u_prev,
                                           const float* __restrict__ Wt_w,
                                           const float* __restrict__ Wt_b,
                                           const float* __restrict__ H_w,
                                           const float* __restrict__ H_b,
                                           float* __restrict__ u_out,   // may be null
                                           float* unew /*LDS[EMB]*/) {
    __shared__ float red[NHOP];
    __shared__ float wop[2][EMB];
    __shared__ float tga[2][EMB], hga[2][EMB];
    __shared__ float us[EMB], wo[EMB];
    __shared__ float gsum_sh;
    int t = threadIdx.x;
    red[t] = bsumP[t];
    __syncthreads();
    for (int st = 128; st > 0; st >>= 1) {
        if (t < st) red[t] += red[t + st];
        __syncthreads();
    }
    if (t == 0) gsum_sh = red[0];
    int e = t & 127, h = t >> 7;
    float acc = 0.f;
    for (int j = 0; j < NHOP / 2; ++j) acc += wpartP[(h * (NHOP / 2) + j) * EMB + e];
    wop[h][e] = acc;
    if (t < EMB) us[t] = u_prev[t];
    __syncthreads();
    if (t < EMB) wo[t] = (wop[0][t] + wop[1][t]) / gsum_sh;
    __syncthreads();
    // matvecs: row e, k-range [h*64,(h+1)*64)
    const float4* wt4 = (const float4*)(Wt_w + e * EMB + h * 64);
    const float4* hw4 = (const float4*)(H_w + e * EMB + h * 64);
    float tg = 0.f, hp = 0.f;
    #pragma unroll
    for (int q = 0; q < 16; ++q) {
        float4 wv = wt4[q];
        float4 hv = hw4[q];
        int k0 = h * 64 + q * 4;
        tg += wv.x * us[k0] + wv.y * us[k0 + 1] + wv.z * us[k0 + 2] + wv.w * us[k0 + 3];
        hp += hv.x * wo[k0] + hv.y * wo[k0 + 1] + hv.z * wo[k0 + 2] + hv.w * wo[k0 + 3];
    }
    tga[h][e] = tg;
    hga[h][e] = hp;
    __syncthreads();
    if (t < EMB) {
        float tgs = Wt_b[t] + tga[0][t] + tga[1][t];
        float hs  = H_b[t]  + hga[0][t] + hga[1][t];
        float gate = 1.f / (1.f + __expf(-tgs));
        float un = us[t] * (1.f - gate) + hs * gate;
        unew[t] = un;
        if (u_out) u_out[t] = un;   // identical duplicate writes across blocks
    }
    __syncthreads();
}

// ===== k_hop<H>: (H>0: finalize u_H) then hop-H partials for 32 rows ========
template <int H>
__global__ __launch_bounds__(256) void k_hop(const float* __restrict__ min_,
                                             const float* __restrict__ mout,
                                             float* __restrict__ uarr,
                                             const float* __restrict__ Wt_w,
                                             const float* __restrict__ Wt_b,
                                             const float* __restrict__ H_w,
                                             const float* __restrict__ H_b,
                                             float* __restrict__ bsum_all,
                                             float* __restrict__ wpart_all) {
    __shared__ float unew[EMB];
    __shared__ float2 su2[64];
    __shared__ float wgt[HROWS];
    __shared__ float part[EMB];
    int b = blockIdx.x, t = threadIdx.x;
    if (H > 0) {
        finalize_u(bsum_all + (H - 1) * NHOP, wpart_all + (H - 1) * NHOP * EMB,
                   uarr + (H - 1) * EMB, Wt_w, Wt_b, H_w, H_b,
                   uarr + H * EMB, unew);
        if (t < 64) su2[t] = ((const float2*)unew)[t];
    } else {
        if (t < 64) su2[t] = ((const float2*)uarr)[t];
    }
    __syncthreads();
    float* bsum = bsum_all + H * NHOP;
    float* wpart = wpart_all + H * NHOP * EMB;
    int w = t >> 6, l = t & 63;
    float2 uv = su2[l];
    int n0 = b * HROWS;
    #pragma unroll
    for (int r = 0; r < HROWS / 4; ++r) {
        int rl = w * (HROWS / 4) + r;
        float2 m = ((const float2*)(min_ + (n0 + rl) * EMB))[l];
        float p = uv.x * m.x + uv.y * m.y;
        #pragma unroll
        for (int o = 32; o > 0; o >>= 1) p += __shfl_xor(p, o);
        if (l == 0) wgt[rl] = __expf(p);
    }
    __syncthreads();
    if (t < HROWS) {
        float s = wgt[t];
        #pragma unroll
        for (int o = HROWS / 2; o > 0; o >>= 1) s += __shfl_xor(s, o);
        if (t == 0) bsum[b] = s;
    }
    int c = t & 127, h = t >> 7;
    float acc = 0.f;
    #pragma unroll
    for (int r = 0; r < HROWS / 2; ++r) {
        int rl = h * (HROWS / 2) + r;
        acc += wgt[rl] * mout[(n0 + rl) * EMB + c];
    }
    if (h == 0) part[c] = acc;
    __syncthreads();
    if (h == 1) wpart[b * EMB + c] = part[c] + acc;
}

// ===== k_logits: finalize u3, then 64 vocab rows per block ==================
__global__ __launch_bounds__(256) void k_logits(const float* __restrict__ W,
                                                float* __restrict__ uarr,
                                                const float* __restrict__ Wt_w,
                                                const float* __restrict__ Wt_b,
                                                const float* __restrict__ H_w,
                                                const float* __restrict__ H_b,
                                                const float* __restrict__ bsum_all,
                                                const float* __restrict__ wpart_all,
                                                float* __restrict__ logits,
                                                float* __restrict__ bpart) {
    __shared__ float unew[EMB];
    __shared__ float es[8];
    int t = threadIdx.x;
    finalize_u(bsum_all + 2 * NHOP, wpart_all + 2 * NHOP * EMB,
               uarr + 2 * EMB, Wt_w, Wt_b, H_w, H_b, nullptr, unew);
    int hw = t >> 5;
    int l2 = t & 31;
    float4 uv = ((const float4*)unew)[l2];
    int v0 = blockIdx.x * LOGROWS + hw * 8;
    float p[8];
    #pragma unroll
    for (int r = 0; r < 8; ++r) {
        int vc = v0 + r; vc = (vc < VOC) ? vc : (VOC - 1);
        float4 wv = ((const float4*)(W + vc * EMB))[l2];
        p[r] = uv.x * wv.x + uv.y * wv.y + uv.z * wv.z + uv.w * wv.w;
    }
    float esum = 0.f;
    #pragma unroll
    for (int r = 0; r < 8; ++r) {
        #pragma unroll
        for (int o = 16; o > 0; o >>= 1) p[r] += __shfl_xor(p[r], o);
        int v = v0 + r;
        if (l2 == 0 && v < VOC) { logits[v] = p[r]; esum += __expf(p[r]); }
    }
    if (l2 == 0) es[hw] = esum;
    __syncthreads();
    if (t == 0) {
        float s = 0.f;
        #pragma unroll
        for (int j = 0; j < 8; ++j) s += es[j];
        bpart[blockIdx.x] = s;
    }
}

// each block redundantly reduces bpart[NLOG] (L2-hot), then writes its slice
__global__ void k_out(const float* __restrict__ logits, const float* __restrict__ bpart,
                      float* __restrict__ out) {
    __shared__ float red[256];
    int t = threadIdx.x;
    float s = 0.f;
    for (int i = t; i < NLOG; i += 256) s += bpart[i];
    red[t] = s; __syncthreads();
    for (int st = 128; st > 0; st >>= 1) {
        if (t < st) red[t] += red[t + st];
        __syncthreads();
    }
    float lse = __logf(red[0]);
    int v = blockIdx.x * 256 + t;
    if (v < VOC) out[v] = logits[v] - lse;
}

extern "C" void kernel_launch(void* const* d_in, const int* in_sizes, int n_in,
                              void* d_out, int out_size, void* d_ws, size_t ws_size,
                              hipStream_t stream) {
    const int*   query = (const int*)d_in[0];
    const int*   story = (const int*)d_in[1];
    const float* Wa    = (const float*)d_in[2];
    const float* Wc    = (const float*)d_in[3];
    const float* Wb    = (const float*)d_in[4];
    const float* Wt_w  = (const float*)d_in[5];
    const float* Wt_b  = (const float*)d_in[6];
    const float* H_w   = (const float*)d_in[7];
    const float* H_b   = (const float*)d_in[8];
    const float* Wout  = (const float*)d_in[9];
    const float* TA    = (const float*)d_in[10];
    const float* TC    = (const float*)d_in[11];
    float* out = (float*)d_out;
    float* ws = (float*)d_ws;

    float* uarr   = ws + WS_U;      // u0..u3
    float* min_   = ws + WS_MIN;
    float* mout   = ws + WS_MOUT;
    float* bsum   = ws + WS_BSUM;   // [3][NHOP]
    float* wpart  = ws + WS_WPART;  // [3][NHOP][EMB]
    float* logits = ws + WS_LOGITS;
    float* bpart  = ws + WS_BPART;

    k_mem_u<<<NMEMBLK + 1, 256, 0, stream>>>(story, query, Wa, Wc, Wb, TA, TC,
                                             min_, mout, uarr);
    k_hop<0><<<NHOP, 256, 0, stream>>>(min_, mout, uarr, Wt_w, Wt_b, H_w, H_b,
                                       bsum, wpart);
    k_hop<1><<<NHOP, 256, 0, stream>>>(min_, mout, uarr, Wt_w, Wt_b, H_w, H_b,
                                       bsum, wpart);
    k_hop<2><<<NHOP, 256, 0, stream>>>(min_, mout, uarr, Wt_w, Wt_b, H_w, H_b,
                                       bsum, wpart);
    k_logits<<<NLOG, 256, 0, stream>>>(Wout, uarr, Wt_w, Wt_b, H_w, H_b,
                                       bsum, wpart, logits, bpart);
    k_out<<<(VOC + 255) / 256, 256, 0, stream>>>(logits, bpart, out);
}

// Round 12
// 259.807 us; speedup vs baseline: 1.2677x; 1.2677x over previous
//
#include <hip/hip_runtime.h>

#define VOC 50257
#define EMB 128
#define NMEM 8192
#define TQ 50
#define TM 50
#define NHOPS 3

#define MEM_ROWS 4                    // rows per k_mem_u block (1 per wave)
#define NMEMBLK (NMEM / MEM_ROWS)     // 2048
#define NHB 64                        // blocks per hop kernel
#define HR (NMEM / NHB)               // 128 rows per hop block
#define WR (HR / 4)                   // 32 rows per wave
#define LOGROWS 64                    // vocab rows per k_logits block
#define NLOG ((VOC + LOGROWS - 1) / LOGROWS)   // 786

// ---------------- workspace layout (float offsets) ----------------
#define WS_U      0                            // u[4][128]: u0..u3
#define WS_MIN    (WS_U + 4*EMB)
#define WS_MOUT   (WS_MIN + NMEM*EMB)
#define WS_BSUM   (WS_MOUT + NMEM*EMB)         // [3][NHB]
#define WS_WPART  (WS_BSUM + 3*NHB)            // [3][NHB][EMB]
#define WS_LOGITS (WS_WPART + 3*NHB*EMB)
#define WS_BPART  (WS_LOGITS + VOC)            // [NLOG]

// ================= k_mem_u: unchanged (proven, absmax 0.0) =================
__global__ void k_mem_u(const int* __restrict__ story, const int* __restrict__ query,
                        const float* __restrict__ Wa, const float* __restrict__ Wc,
                        const float* __restrict__ Wb, const float* __restrict__ TA,
                        const float* __restrict__ TC, float* __restrict__ min_,
                        float* __restrict__ mout, float* __restrict__ u) {
    int b = blockIdx.x;
    int t = threadIdx.x;
    if (b == NMEMBLK) {
        __shared__ int q[TQ];
        if (t < TQ) q[t] = query[t];
        __syncthreads();
        if (t < EMB) {
            float acc = 0.f;
            for (int i = 0; i < TQ; ++i) acc += Wb[q[i] * EMB + t];
            u[t] = acc;
        }
        return;
    }
    __shared__ int toks[MEM_ROWS * TM];
    if (t < MEM_ROWS * TM) toks[t] = story[b * MEM_ROWS * TM + t];
    __syncthreads();
    int w = t >> 6;
    int lane = t & 63;
    int half = lane >> 5;
    int l = lane & 31;
    int n = b * MEM_ROWS + w;
    float4 a = {0.f, 0.f, 0.f, 0.f};
    float4 c = {0.f, 0.f, 0.f, 0.f};
    #pragma unroll
    for (int tt = 0; tt < TM / 2; ++tt) {
        int tok = toks[w * TM + 2 * tt + half];
        float4 va = ((const float4*)(Wa + tok * EMB))[l];
        float4 vc = ((const float4*)(Wc + tok * EMB))[l];
        a.x += va.x; a.y += va.y; a.z += va.z; a.w += va.w;
        c.x += vc.x; c.y += vc.y; c.z += vc.z; c.w += vc.w;
    }
    a.x += __shfl_xor(a.x, 32); a.y += __shfl_xor(a.y, 32);
    a.z += __shfl_xor(a.z, 32); a.w += __shfl_xor(a.w, 32);
    c.x += __shfl_xor(c.x, 32); c.y += __shfl_xor(c.y, 32);
    c.z += __shfl_xor(c.z, 32); c.w += __shfl_xor(c.w, 32);
    if (half == 0) {
        float4 tv = ((const float4*)(TA + n * EMB))[l];
        a.x += tv.x; a.y += tv.y; a.z += tv.z; a.w += tv.w;
        ((float4*)(min_ + n * EMB))[l] = a;
    } else {
        float4 tv = ((const float4*)(TC + n * EMB))[l];
        c.x += tv.x; c.y += tv.y; c.z += tv.z; c.w += tv.w;
        ((float4*)(mout + n * EMB))[l] = c;
    }
}

// ===== finalize: u_new from prev-hop partials (validated math, R8) =========
// bsumP[NHB], wpartP[NHB][EMB] -> unew (LDS); optional global write.
__device__ __forceinline__ void finalize_u(const float* __restrict__ bsumP,
                                           const float* __restrict__ wpartP,
                                           const float* __restrict__ u_prev,
                                           const float* __restrict__ Wt_w,
                                           const float* __restrict__ Wt_b,
                                           const float* __restrict__ H_w,
                                           const float* __restrict__ H_b,
                                           float* __restrict__ u_out,   // may be null
                                           float* unew /*LDS[EMB]*/) {
    __shared__ float wop[2][EMB];
    __shared__ float tga[2][EMB], hga[2][EMB];
    __shared__ float us[EMB], wo[EMB];
    __shared__ float gsum_sh;
    int t = threadIdx.x;
    if (t < NHB) {
        float s = bsumP[t];
        #pragma unroll
        for (int o = 32; o > 0; o >>= 1) s += __shfl_xor(s, o);
        if (t == 0) gsum_sh = s;
    }
    int e = t & 127, h = t >> 7;
    float acc = 0.f;
    #pragma unroll 8
    for (int j = 0; j < NHB / 2; ++j) acc += wpartP[(h * (NHB / 2) + j) * EMB + e];
    wop[h][e] = acc;
    if (t < EMB) us[t] = u_prev[t];
    __syncthreads();
    if (t < EMB) wo[t] = (wop[0][t] + wop[1][t]) / gsum_sh;
    __syncthreads();
    const float4* wt4 = (const float4*)(Wt_w + e * EMB + h * 64);
    const float4* hw4 = (const float4*)(H_w + e * EMB + h * 64);
    float tg = 0.f, hp = 0.f;
    #pragma unroll
    for (int q = 0; q < 16; ++q) {
        float4 wv = wt4[q];
        float4 hv = hw4[q];
        int k0 = h * 64 + q * 4;
        tg += wv.x * us[k0] + wv.y * us[k0 + 1] + wv.z * us[k0 + 2] + wv.w * us[k0 + 3];
        hp += hv.x * wo[k0] + hv.y * wo[k0 + 1] + hv.z * wo[k0 + 2] + hv.w * wo[k0 + 3];
    }
    tga[h][e] = tg;
    hga[h][e] = hp;
    __syncthreads();
    if (t < EMB) {
        float tgs = Wt_b[t] + tga[0][t] + tga[1][t];
        float hs  = H_b[t]  + hga[0][t] + hga[1][t];
        float gate = 1.f / (1.f + __expf(-tgs));
        float un = us[t] * (1.f - gate) + hs * gate;
        unew[t] = un;
        if (u_out) u_out[t] = un;
    }
    __syncthreads();
}

// ===== k_hop<H>: (H>0: redundant finalize of u_H, 32KB read) + hop-H ======
template <int H>
__global__ __launch_bounds__(256) void k_hop(const float* __restrict__ min_,
                                             const float* __restrict__ mout,
                                             float* __restrict__ uarr,
                                             const float* __restrict__ Wt_w,
                                             const float* __restrict__ Wt_b,
                                             const float* __restrict__ H_w,
                                             const float* __restrict__ H_b,
                                             float* __restrict__ bsum_all,
                                             float* __restrict__ wpart_all) {
    __shared__ float unew[EMB];
    __shared__ float2 su2[64];
    __shared__ float wgt[HR];
    __shared__ float part[EMB];
    __shared__ float bs2[2];
    int b = blockIdx.x, t = threadIdx.x;
    if (H > 0) {
        finalize_u(bsum_all + (H - 1) * NHB, wpart_all + (H - 1) * NHB * EMB,
                   uarr + (H - 1) * EMB, Wt_w, Wt_b, H_w, H_b,
                   (b == 0) ? (uarr + H * EMB) : nullptr, unew);
        if (t < 64) su2[t] = ((const float2*)unew)[t];
    } else {
        if (t < 64) su2[t] = ((const float2*)uarr)[t];
    }
    __syncthreads();
    float* bsum  = bsum_all + H * NHB;
    float* wpart = wpart_all + H * NHB * EMB;
    int w = t >> 6, l = t & 63;
    float2 uv = su2[l];
    int n0 = b * HR;
    #pragma unroll 4
    for (int r = 0; r < WR; ++r) {
        int rl = w * WR + r;
        float2 m = ((const float2*)(min_ + (n0 + rl) * EMB))[l];
        float p = uv.x * m.x + uv.y * m.y;
        #pragma unroll
        for (int o = 32; o > 0; o >>= 1) p += __shfl_xor(p, o);
        if (l == 0) wgt[rl] = __expf(p);
    }
    __syncthreads();
    if (t < HR) {
        float s = wgt[t];
        #pragma unroll
        for (int o = 32; o > 0; o >>= 1) s += __shfl_xor(s, o);
        if ((t & 63) == 0) bs2[t >> 6] = s;
    }
    __syncthreads();
    if (t == 0) bsum[b] = bs2[0] + bs2[1];
    int c = t & 127, h = t >> 7;
    float acc = 0.f;
    #pragma unroll 8
    for (int r = 0; r < HR / 2; ++r) {
        int rl = h * (HR / 2) + r;
        acc += wgt[rl] * mout[(n0 + rl) * EMB + c];
    }
    if (h == 0) part[c] = acc;
    __syncthreads();
    if (h == 1) wpart[b * EMB + c] = part[c] + acc;
}

// ===== k_fin: single block, finalize u2 -> u3 (global) =====================
__global__ __launch_bounds__(256) void k_fin(float* __restrict__ uarr,
                                             const float* __restrict__ Wt_w,
                                             const float* __restrict__ Wt_b,
                                             const float* __restrict__ H_w,
                                             const float* __restrict__ H_b,
                                             const float* __restrict__ bsum_all,
                                             const float* __restrict__ wpart_all) {
    __shared__ float unew[EMB];
    finalize_u(bsum_all + 2 * NHB, wpart_all + 2 * NHB * EMB,
               uarr + 2 * EMB, Wt_w, Wt_b, H_w, H_b, uarr + 3 * EMB, unew);
}

// ===== k_logits: reads clean u3[128]; 64 vocab rows/block (validated R6) ===
__global__ __launch_bounds__(256) void k_logits(const float* __restrict__ W,
                                                const float* __restrict__ u3,
                                                float* __restrict__ logits,
                                                float* __restrict__ bpart) {
    __shared__ float4 su[32];
    __shared__ float es[8];
    int t = threadIdx.x;
    if (t < 32) su[t] = ((const float4*)u3)[t];
    __syncthreads();
    int hw = t >> 5;       // half-wave 0..7
    int l2 = t & 31;
    float4 uv = su[l2];
    int v0 = blockIdx.x * LOGROWS + hw * 8;
    float p[8];
    #pragma unroll
    for (int r = 0; r < 8; ++r) {
        int vc = v0 + r; vc = (vc < VOC) ? vc : (VOC - 1);   // clamp -> unconditional load
        float4 wv = ((const float4*)(W + vc * EMB))[l2];
        p[r] = uv.x * wv.x + uv.y * wv.y + uv.z * wv.z + uv.w * wv.w;
    }
    float esum = 0.f;
    #pragma unroll
    for (int r = 0; r < 8; ++r) {
        #pragma unroll
        for (int o = 16; o > 0; o >>= 1) p[r] += __shfl_xor(p[r], o);
        int v = v0 + r;
        if (l2 == 0 && v < VOC) { logits[v] = p[r]; esum += __expf(p[r]); }
    }
    if (l2 == 0) es[hw] = esum;
    __syncthreads();
    if (t == 0) {
        float s = 0.f;
        #pragma unroll
        for (int j = 0; j < 8; ++j) s += es[j];
        bpart[blockIdx.x] = s;
    }
}

// each block redundantly reduces bpart[NLOG] (L2-hot), then writes its slice
__global__ void k_out(const float* __restrict__ logits, const float* __restrict__ bpart,
                      float* __restrict__ out) {
    __shared__ float red[256];
    int t = threadIdx.x;
    float s = 0.f;
    for (int i = t; i < NLOG; i += 256) s += bpart[i];
    red[t] = s; __syncthreads();
    for (int st = 128; st > 0; st >>= 1) {
        if (t < st) red[t] += red[t + st];
        __syncthreads();
    }
    float lse = __logf(red[0]);
    int v = blockIdx.x * 256 + t;
    if (v < VOC) out[v] = logits[v] - lse;
}

extern "C" void kernel_launch(void* const* d_in, const int* in_sizes, int n_in,
                              void* d_out, int out_size, void* d_ws, size_t ws_size,
                              hipStream_t stream) {
    const int*   query = (const int*)d_in[0];
    const int*   story = (const int*)d_in[1];
    const float* Wa    = (const float*)d_in[2];
    const float* Wc    = (const float*)d_in[3];
    const float* Wb    = (const float*)d_in[4];
    const float* Wt_w  = (const float*)d_in[5];
    const float* Wt_b  = (const float*)d_in[6];
    const float* H_w   = (const float*)d_in[7];
    const float* H_b   = (const float*)d_in[8];
    const float* Wout  = (const float*)d_in[9];
    const float* TA    = (const float*)d_in[10];
    const float* TC    = (const float*)d_in[11];
    float* out = (float*)d_out;
    float* ws = (float*)d_ws;

    float* uarr   = ws + WS_U;      // u0..u3
    float* min_   = ws + WS_MIN;
    float* mout   = ws + WS_MOUT;
    float* bsum   = ws + WS_BSUM;   // [3][NHB]
    float* wpart  = ws + WS_WPART;  // [3][NHB][EMB]
    float* logits = ws + WS_LOGITS;
    float* bpart  = ws + WS_BPART;

    k_mem_u<<<NMEMBLK + 1, 256, 0, stream>>>(story, query, Wa, Wc, Wb, TA, TC,
                                             min_, mout, uarr);
    k_hop<0><<<NHB, 256, 0, stream>>>(min_, mout, uarr, Wt_w, Wt_b, H_w, H_b,
                                      bsum, wpart);
    k_hop<1><<<NHB, 256, 0, stream>>>(min_, mout, uarr, Wt_w, Wt_b, H_w, H_b,
                                      bsum, wpart);
    k_hop<2><<<NHB, 256, 0, stream>>>(min_, mout, uarr, Wt_w, Wt_b, H_w, H_b,
                                      bsum, wpart);
    k_fin<<<1, 256, 0, stream>>>(uarr, Wt_w, Wt_b, H_w, H_b, bsum, wpart);
    k_logits<<<NLOG, 256, 0, stream>>>(Wout, uarr + 3 * EMB, logits, bpart);
    k_out<<<(VOC + 255) / 256, 256, 0, stream>>>(logits, bpart, out);
}